// Round 11
// baseline (237.779 us; speedup 1.0000x reference)
//
#include <hip/hip_runtime.h>

typedef __bf16 bf16x8 __attribute__((ext_vector_type(8)));
typedef float f32x4 __attribute__((ext_vector_type(4)));
typedef unsigned short u16;
typedef unsigned int u32;
typedef unsigned long long u64;
typedef u16 u16x8 __attribute__((ext_vector_type(8)));

#define TID ((int)threadIdx.x)

constexpr int Nn = 64, Tt = 300, Vv = 25;
constexpr int Fin = 1600;           // V*C = V*CO
constexpr int RowsT = 19200;        // N*T
constexpr int TBR = 12;             // t-rows per block; 300 = 25*12 -> NO TAIL
constexpr int NTB = 25;             // 300/12
constexpr int NBLK = Nn * NTB;      // 1600 tiles
constexpr int RAWE = 64 * 300;      // 19200 bf16 (38400 B), layout [c][t*25+v], t<12
constexpr int YROW = 1604;          // ylds row stride (word-offset 802 = 2 mod 32)
constexpr int EPI_OFF = 38496;      // byte offset of epi in smem (12*1604*2, 8B-aligned)
constexpr int SMEM_SZ = EPI_OFF + 12800;  // 51296 B -> 3 blocks/CU
constexpr float EPSv = 1e-5f;

// d_ws layout:
//   [0, 12800)            wsum_final: 1600 sum + 1600 sumsq (f32)
//   [12800, 25600)        epi_g: u64[1600] folded BN, permuted to d*25+v
//   [25600, 33792)        wv:    u16[4096] plain-W B-fragments (v-independent)
//   [33792, 40192)        combo_g: u32[1600] (gather_off<<16)|bf16(tanh(fm)+1)
//   [40192, 20520192)     part: f32[1600][3200] block partials (20.48 MB)
constexpr int WS_EPI   = 12800;
constexpr int WS_WV    = 25600;
constexpr int WS_COMBO = 33792;
constexpr int WS_PART  = 40192;
constexpr size_t WS_NEED_PART = (size_t)WS_PART + (size_t)NBLK * 3200 * 4;

__device__ __forceinline__ u16 f2b(float f) {
  u32 u = __float_as_uint(f);
  return (u16)((u + 0x7fffu + ((u >> 16) & 1u)) >> 16); // RNE
}
__device__ __forceinline__ float b2f(u16 h) {
  return __uint_as_float(((u32)h) << 16);
}
__device__ __forceinline__ u64 pack4(float a, float b, float c, float d) {
  return (u64)f2b(a) | ((u64)f2b(b) << 16) | ((u64)f2b(c) << 32) | ((u64)f2b(d) << 48);
}

// ---- stage x-tile as bf16, layout [c][t*25+v], t in [0,12) — always full ----
__device__ __forceinline__ void stage_raw(const float* __restrict__ x,
                                          int n, int tb, u16* raw) {
  const int base = n * 480000 + tb * 300;   // (n, c=0, t0, v=0); t0*25 = tb*300
  #pragma unroll
  for (int i = 0; i < 10; ++i) {
    int q = TID + i * 512;                  // float4 group id, 0..4799
    if (q < 4800) {
      int c = q / 75;
      int g4 = (q - c * 75) * 4;            // 0..296, 16B aligned
      float4 xv = *reinterpret_cast<const float4*>(x + base + c * 7500 + g4);
      *reinterpret_cast<u64*>(raw + q * 4) = pack4(xv.x, xv.y, xv.z, xv.w);
    }
  }
}

// 8 v-independent B fragments (plain W) -> registers, one coalesced pass
__device__ __forceinline__ void load_bfr_g(const u16* __restrict__ wv, bf16x8 bfr[2][4]) {
  int l = TID & 63;
  #pragma unroll
  for (int ks = 0; ks < 2; ++ks)
    #pragma unroll
    for (int nt = 0; nt < 4; ++nt)
      bfr[ks][nt] = *reinterpret_cast<const bf16x8*>(wv + ((((ks << 2) | nt) << 9) + l * 8));
}

// A fragment: gather+mask from LDS; combo table from L2; t=lane&15; rows t>=12 zeroed
__device__ __forceinline__ bf16x8 build_a(const u16* raw, const u32* __restrict__ combo,
                                          int v, int ks, int t, int grp) {
  int jb = v * 64 + ks * 32 + grp * 8;
  bf16x8 a;
  #pragma unroll
  for (int i = 0; i < 8; ++i) {
    u32 cb = combo[jb + i];
    float m = __uint_as_float((cb & 0xffffu) << 16);
    float xv = b2f(raw[(cb >> 16) + t * 25]);
    a[i] = (__bf16)(xv * m);
  }
  if (t >= TBR) {                           // zero pad rows -> 0 contribution
    u64* p = reinterpret_cast<u64*>(&a);
    p[0] = 0; p[1] = 0;
  }
  return a;
}

// ---- precompute: zero wsum_final; combo (tanh hoisted); plain-W B fragments ----
__global__ void k_wv(const float* __restrict__ lin_w, const float* __restrict__ feat_mask,
                     const int* __restrict__ shift_in, float* __restrict__ wsum,
                     u16* __restrict__ wv, u32* __restrict__ combo_g) {
  int gid = blockIdx.x * 256 + TID;       // grid 13*256 = 3328
  if (gid < 3200) wsum[gid] = 0.f;        // atomic-mode target (re-zeroed each launch)
  if (gid < Fin) {
    int s = shift_in[gid];                               // source col v2*64+c2
    u32 off = (u32)((s & 63) * 300 + (s >> 6));          // raw idx c2*300 + v2
    float m = tanhf(feat_mask[gid]) + 1.0f;
    combo_g[gid] = (off << 16) | (u32)f2b(m);
  }
  if (gid >= 2048 && gid < 2560) {        // 512 threads build B fragments
    int t = gid - 2048;
    int l = t & 63, nt = (t >> 6) & 3, ks = t >> 8;
    int c0 = ks * 32 + (l >> 4) * 8, d = nt * 16 + (l & 15);
    u16x8 o8;
    #pragma unroll
    for (int i = 0; i < 8; ++i) o8[i] = f2b(lin_w[(c0 + i) * 64 + d]);
    *reinterpret_cast<u16x8*>(wv + ((((ks << 2) | nt) << 9) + l * 8)) = o8;
  }
}

// stats pass: areg hoist first, bfr after (anti-spill), then MFMA + reduce + stores
template <int ATOMIC>
__global__ __launch_bounds__(512, 6) void k_stats(
    const float* __restrict__ x, const u16* __restrict__ wv,
    const u32* __restrict__ combo_g, float* __restrict__ target)
{
  __shared__ __align__(16) u16 raw[RAWE];   // 38.4 KB
  int bid = blockIdx.x;                   // 0..1599, 1 tile each
  int n = bid / NTB, tb = bid - n * NTB;
  int w = TID >> 6, l = TID & 63;
  int t_lane = l & 15, grp = l >> 4;

  stage_raw(x, n, tb, raw);
  __syncthreads();

  // phase 2: hoist A fragments (bfr NOT yet live)
  bf16x8 areg[4][2];
  #pragma unroll
  for (int k = 0; k < 4; ++k) {
    int v = w + 8 * k;
    if (v < Vv) {
      areg[k][0] = build_a(raw, combo_g, v, 0, t_lane, grp);
      areg[k][1] = build_a(raw, combo_g, v, 1, t_lane, grp);
    }
  }

  // phase 3: B fragments now, then MFMA + stat reduce
  bf16x8 bfr[2][4];
  load_bfr_g(wv, bfr);

  float* pb = target + (ATOMIC ? 0 : bid * 3200);
  #pragma unroll
  for (int k = 0; k < 4; ++k) {
    int v = w + 8 * k;
    if (v < Vv) {
      float pr[4], qr[4];
      #pragma unroll
      for (int nt = 0; nt < 4; ++nt) {
        f32x4 acc = {0.f, 0.f, 0.f, 0.f};
        acc = __builtin_amdgcn_mfma_f32_16x16x32_bf16(areg[k][0], bfr[0][nt], acc, 0, 0, 0);
        acc = __builtin_amdgcn_mfma_f32_16x16x32_bf16(areg[k][1], bfr[1][nt], acc, 0, 0, 0);
        // zeroed A rows (t>=12) contribute 0 to both sums
        float pp = acc[0] + acc[1] + acc[2] + acc[3];
        float qq = acc[0]*acc[0] + acc[1]*acc[1] + acc[2]*acc[2] + acc[3]*acc[3];
        pp += __shfl_xor(pp, 16); pp += __shfl_xor(pp, 32);   // all-reduce
        qq += __shfl_xor(qq, 16); qq += __shfl_xor(qq, 32);
        pr[nt] = pp; qr[nt] = qq;
      }
      if (ATOMIC) {
        if ((l & 48) == 0) {
          #pragma unroll
          for (int nt = 0; nt < 4; ++nt) {
            int col = v * 64 + nt * 16 + t_lane;
            atomicAdd(&pb[col], pr[nt]);
            atomicAdd(&pb[1600 + col], qr[nt]);
          }
        }
      } else {
        // full-wave 256B coalesced partial stores (lane picks its fragment)
        float pv = (grp & 2) ? ((grp & 1) ? pr[3] : pr[2]) : ((grp & 1) ? pr[1] : pr[0]);
        float qv = (grp & 2) ? ((grp & 1) ? qr[3] : qr[2]) : ((grp & 1) ? qr[1] : qr[0]);
        pb[v * 64 + l] = pv;
        pb[1600 + v * 64 + l] = qv;
      }
    }
  }
}

// reduce part[1600][3200] -> wsum_final[3200]; 200 blocks x (16 cols x 16 chunks)
__global__ __launch_bounds__(256) void k_red(const float* __restrict__ part,
                                             float* __restrict__ wsum) {
  __shared__ float red[16 * 17];
  int col0 = blockIdx.x * 16;
  int c = TID & 15, ch = TID >> 4;        // ch 0..15, 100 rows each
  float s = 0.f;
  int r0 = ch * 100;
  #pragma unroll 4
  for (int i = 0; i < 100; ++i) s += part[(r0 + i) * 3200 + col0 + c];
  red[ch * 17 + c] = s;
  __syncthreads();
  if (TID < 16) {
    float t = 0.f;
    #pragma unroll
    for (int j = 0; j < 16; ++j) t += red[j * 17 + TID];
    wsum[col0 + TID] = t;
  }
}

// BN fold once: entry {f32 scale, bf16 off, u16 s2} at permuted index d*25+v
__global__ void k_epi(const float* __restrict__ wsum, const float* __restrict__ gamma,
                      const float* __restrict__ beta, const int* __restrict__ shift_out,
                      u64* __restrict__ epi_g) {
  int k = blockIdx.x * 256 + TID;
  if (k >= Fin) return;
  int s2 = shift_out[k];
  float sm = wsum[s2] * (1.0f / RowsT);
  float sq = wsum[1600 + s2] * (1.0f / RowsT);
  float rstd = rsqrtf(fmaxf(sq - sm * sm, 0.f) + EPSv);
  float sc = gamma[k] * rstd;             // lin_b provably cancels in BN
  int d = k & 63, v = k >> 6;
  epi_g[d * 25 + v] = (u64)__float_as_uint(sc)
                    | ((u64)f2b(beta[k] - sm * sc) << 32)
                    | ((u64)(u32)s2 << 48);
}

// consumer: recompute y into t-major LDS; epi in LDS; 51.3 KB -> 3 blocks/CU
__global__ __launch_bounds__(512, 6) void k_main(
    const float* __restrict__ x, const u16* __restrict__ wv,
    const u32* __restrict__ combo_g, const u64* __restrict__ epi_g,
    float* __restrict__ out)
{
  // [0, 38400) raw  --overlay-->  ylds bf16[12][1604] [0, 38496)
  // [38496, 51296) epi u64[1600] persistent
  __shared__ __align__(16) unsigned char smem[SMEM_SZ];
  u16* raw  = reinterpret_cast<u16*>(smem);
  u16* ylds = reinterpret_cast<u16*>(smem);
  u64* epi  = reinterpret_cast<u64*>(smem + EPI_OFF);

  int bid = blockIdx.x;
  int n = bid / NTB, tb = bid - n * NTB;

  stage_raw(x, n, tb, raw);
  #pragma unroll
  for (int i = 0; i < 4; ++i) {
    int j = TID + i * 512;
    if (j < Fin) epi[j] = epi_g[j];
  }
  __syncthreads();

  // phase 2: hoist A fragments (bfr NOT yet live); raw dies after this
  int w = TID >> 6, l = TID & 63, grp = l >> 4, t_lane = l & 15;
  bf16x8 areg[4][2];
  #pragma unroll
  for (int k = 0; k < 4; ++k) {
    int v = w + 8 * k;
    if (v < Vv) {
      areg[k][0] = build_a(raw, combo_g, v, 0, t_lane, grp);
      areg[k][1] = build_a(raw, combo_g, v, 1, t_lane, grp);
    }
  }
  __syncthreads();  // overlay region now ylds

  // phase 3: B fragments, MFMA -> t-major ylds (grp 3 rows t>=12 dropped)
  bf16x8 bfr[2][4];
  load_bfr_g(wv, bfr);

  #pragma unroll
  for (int k = 0; k < 4; ++k) {
    int v = w + 8 * k;
    if (v < Vv) {
      #pragma unroll
      for (int nt = 0; nt < 4; ++nt) {
        f32x4 acc = {0.f, 0.f, 0.f, 0.f};
        acc = __builtin_amdgcn_mfma_f32_16x16x32_bf16(areg[k][0], bfr[0][nt], acc, 0, 0, 0);
        acc = __builtin_amdgcn_mfma_f32_16x16x32_bf16(areg[k][1], bfr[1][nt], acc, 0, 0, 0);
        if (grp < 3) {
          int col = v * 64 + nt * 16 + t_lane;
          #pragma unroll
          for (int j = 0; j < 4; ++j)
            ylds[(grp * 4 + j) * YROW + col] = f2b(acc[j]);
        }
      }
    }
  }
  __syncthreads();

  // epilogue: BN + residual (x re-read, L3-hot) + relu, float4 stores
  const int obase = n * 480000 + tb * 300;
  #pragma unroll
  for (int it = 0; it < 10; ++it) {
    int g = TID + it * 512;               // float4 group id, 0..4799
    if (g < 4800) {
      int d = g / 75;
      int f0 = (g - d * 75) * 4;          // 0..296
      const float4 xr = *reinterpret_cast<const float4*>(x + obase + d * 7500 + f0);
      float4 o;
      float* op = &o.x;
      const float* xp = &xr.x;
      #pragma unroll
      for (int e = 0; e < 4; ++e) {
        int f = f0 + e;
        int t = f / 25;
        int v = f - t * 25;
        u64 ep = epi[d * 25 + v];         // LDS
        float sc = __uint_as_float((u32)ep);
        float of = b2f((u16)(ep >> 32));
        float y = b2f(ylds[t * YROW + (int)(ep >> 48)]);
        op[e] = fmaxf(fmaf(y, sc, of) + xp[e], 0.f);
      }
      *reinterpret_cast<float4*>(out + obase + d * 7500 + f0) = o;
    }
  }
}

extern "C" void kernel_launch(void* const* d_in, const int* in_sizes, int n_in,
                              void* d_out, int out_size, void* d_ws, size_t ws_size,
                              hipStream_t stream) {
  (void)in_sizes; (void)n_in; (void)out_size;
  const float* x        = (const float*)d_in[0];
  const float* lin_w    = (const float*)d_in[1];
  // d_in[2] = lin_b: provably cancels in BatchNorm -> unused
  const float* feat_mask= (const float*)d_in[3];
  const float* gamma    = (const float*)d_in[4];
  const float* beta     = (const float*)d_in[5];
  const int*   shift_in = (const int*)d_in[6];
  const int*   shift_out= (const int*)d_in[7];
  float* wsum   = (float*)d_ws;
  u64*   epi_g  = (u64*)((char*)d_ws + WS_EPI);
  u16*   wv     = (u16*)((char*)d_ws + WS_WV);
  u32*   combo_g= (u32*)((char*)d_ws + WS_COMBO);
  float* part   = (float*)((char*)d_ws + WS_PART);

  k_wv<<<13, 256, 0, stream>>>(lin_w, feat_mask, shift_in, wsum, wv, combo_g);
  if (ws_size >= WS_NEED_PART) {
    k_stats<0><<<NBLK, 512, 0, stream>>>(x, wv, combo_g, part);
    k_red<<<200, 256, 0, stream>>>(part, wsum);
  } else {
    k_stats<1><<<NBLK, 512, 0, stream>>>(x, wv, combo_g, wsum);
  }
  k_epi <<<7, 256, 0, stream>>>(wsum, gamma, beta, shift_out, epi_g);
  k_main<<<NBLK, 512, 0, stream>>>(x, wv, combo_g, epi_g, (float*)d_out);
}

// Round 12
// 114.786 us; speedup vs baseline: 2.0715x; 2.0715x over previous
//
#include <hip/hip_runtime.h>

typedef __bf16 bf16x8 __attribute__((ext_vector_type(8)));
typedef float f32x4 __attribute__((ext_vector_type(4)));
typedef unsigned short u16;
typedef unsigned int u32;
typedef unsigned long long u64;
typedef u16 u16x8 __attribute__((ext_vector_type(8)));

#define TID ((int)threadIdx.x)

constexpr int Nn = 64, Tt = 300, Vv = 25;
constexpr int Fin = 1600;           // V*C = V*CO
constexpr int RowsT = 19200;        // N*T
constexpr int TBR = 16;             // t-rows per block
constexpr int NTB = 19;             // ceil(300/16)
constexpr int NBLK = Nn * NTB;      // 1216 tiles
constexpr int RAWE = 64 * TBR * Vv; // 25600 bf16 (51200 B); also ylds[1600][16]
constexpr float EPSv = 1e-5f;

// d_ws layout:
//   [0, 12800)            wsum_final: 1600 sum + 1600 sumsq (f32)
//   [12800, 25600)        epi_g: u64[1600] folded BN, permuted to d*25+v
//   [25600, 33792)        wv:    u16[4096] plain-W B-fragments (v-independent)
//   [33792, 40192)        combo_g: u32[1600] (gather_off<<16)|bf16(tanh(fm)+1)
//   [40192, 15604992)     part: f32[1216][3200] block partials (15.56 MB)
constexpr int WS_EPI   = 12800;
constexpr int WS_WV    = 25600;
constexpr int WS_COMBO = 33792;
constexpr int WS_PART  = 40192;
constexpr size_t WS_NEED_PART = (size_t)WS_PART + (size_t)NBLK * 3200 * 4;

__device__ __forceinline__ u16 f2b(float f) {
  u32 u = __float_as_uint(f);
  return (u16)((u + 0x7fffu + ((u >> 16) & 1u)) >> 16); // RNE
}
__device__ __forceinline__ float b2f(u16 h) {
  return __uint_as_float(((u32)h) << 16);
}
__device__ __forceinline__ u64 pack4(float a, float b, float c, float d) {
  return (u64)f2b(a) | ((u64)f2b(b) << 16) | ((u64)f2b(c) << 32) | ((u64)f2b(d) << 48);
}

// ---- stage x-tile as bf16, layout [c][t*25+v] (512 threads) ----
__device__ __forceinline__ void stage_raw(const float* __restrict__ x,
                                          int n, int t0, int validg, u16* raw) {
  const int base = n * 480000 + t0 * 25;
  if (validg == TBR * 25) {
    #pragma unroll
    for (int i = 0; i < 13; ++i) {
      int q = TID + i * 512;              // float4 group id, 0..6399
      if (q < 6400) {
        int c = q / 100;
        int g4 = (q - c * 100) * 4;       // 16B aligned
        float4 xv = *reinterpret_cast<const float4*>(x + base + c * 7500 + g4);
        *reinterpret_cast<u64*>(raw + q * 4) = pack4(xv.x, xv.y, xv.z, xv.w);
      }
    }
  } else {
    #pragma unroll
    for (int i = 0; i < 13; ++i) {
      int q = TID + i * 512;
      if (q < 6400) {
        int c = q / 100;
        int g4 = (q - c * 100) * 4;
        float4 xv = make_float4(0.f, 0.f, 0.f, 0.f);
        if (g4 < validg)                  // validg==300: 4-groups all-or-nothing
          xv = *reinterpret_cast<const float4*>(x + base + c * 7500 + g4);
        *reinterpret_cast<u64*>(raw + q * 4) = pack4(xv.x, xv.y, xv.z, xv.w);
      }
    }
  }
}

// 8 v-independent B fragments (plain W) -> registers, one coalesced pass
__device__ __forceinline__ void load_bfr_g(const u16* __restrict__ wv, bf16x8 bfr[2][4]) {
  int l = TID & 63;
  #pragma unroll
  for (int ks = 0; ks < 2; ++ks)
    #pragma unroll
    for (int nt = 0; nt < 4; ++nt)
      bfr[ks][nt] = *reinterpret_cast<const bf16x8*>(wv + ((((ks << 2) | nt) << 9) + l * 8));
}

// A fragment: gather+mask from LDS; combo from LDS or L2; t=lane&15
__device__ __forceinline__ bf16x8 build_a(const u16* raw, const u32* __restrict__ combo,
                                          int v, int ks, int t, int grp) {
  int jb = v * 64 + ks * 32 + grp * 8;
  bf16x8 a;
  #pragma unroll
  for (int i = 0; i < 8; ++i) {
    u32 cb = combo[jb + i];
    float m = __uint_as_float((cb & 0xffffu) << 16);
    float xv = b2f(raw[(cb >> 16) + t * 25]);
    a[i] = (__bf16)(xv * m);
  }
  return a;
}

// ---- precompute: zero wsum_final; combo (tanh hoisted); plain-W B fragments ----
__global__ void k_wv(const float* __restrict__ lin_w, const float* __restrict__ feat_mask,
                     const int* __restrict__ shift_in, float* __restrict__ wsum,
                     u16* __restrict__ wv, u32* __restrict__ combo_g) {
  int gid = blockIdx.x * 256 + TID;       // grid 13*256 = 3328
  if (gid < 3200) wsum[gid] = 0.f;        // atomic-mode target (re-zeroed each launch)
  if (gid < Fin) {
    int s = shift_in[gid];                               // source col v2*64+c2
    u32 off = (u32)((s & 63) * 400 + (s >> 6));          // raw idx c2*400 + v2
    float m = tanhf(feat_mask[gid]) + 1.0f;
    combo_g[gid] = (off << 16) | (u32)f2b(m);
  }
  if (gid >= 2048 && gid < 2560) {        // 512 threads build B fragments
    int t = gid - 2048;
    int l = t & 63, nt = (t >> 6) & 3, ks = t >> 8;
    int c0 = ks * 32 + (l >> 4) * 8, d = nt * 16 + (l & 15);
    u16x8 o8;
    #pragma unroll
    for (int i = 0; i < 8; ++i) o8[i] = f2b(lin_w[(c0 + i) * 64 + d]);
    *reinterpret_cast<u16x8*>(wv + ((((ks << 2) | nt) << 9) + l * 8)) = o8;
  }
}

// stats pass: ATOMIC=0 stores block partials (coalesced); ATOMIC=1 atomicAdd fallback
template <int ATOMIC>
__global__ __launch_bounds__(512, 4) void k_stats(
    const float* __restrict__ x, const u16* __restrict__ wv,
    const u32* __restrict__ combo_g, float* __restrict__ target)
{
  __shared__ __align__(16) u16 raw[RAWE];   // 51.2 KB
  int bid = blockIdx.x;                   // 0..1215, 1 tile each
  int n = bid / NTB, tb = bid - n * NTB;
  int t0 = tb * TBR;
  int validg = min(TBR, Tt - t0) * 25;
  int w = TID >> 6, l = TID & 63;
  int t_lane = l & 15, grp = l >> 4;

  stage_raw(x, n, t0, validg, raw);
  __syncthreads();

  // phase 2: hoist A fragments (bfr NOT yet live)
  bf16x8 areg[4][2];
  #pragma unroll
  for (int k = 0; k < 4; ++k) {
    int v = w + 8 * k;
    if (v < Vv) {
      areg[k][0] = build_a(raw, combo_g, v, 0, t_lane, grp);
      areg[k][1] = build_a(raw, combo_g, v, 1, t_lane, grp);
    }
  }

  // phase 3: B fragments now, then MFMA + stat reduce
  bf16x8 bfr[2][4];
  load_bfr_g(wv, bfr);

  float* pb = target + (ATOMIC ? 0 : bid * 3200);
  #pragma unroll
  for (int k = 0; k < 4; ++k) {
    int v = w + 8 * k;
    if (v < Vv) {
      float pr[4], qr[4];
      #pragma unroll
      for (int nt = 0; nt < 4; ++nt) {
        f32x4 acc = {0.f, 0.f, 0.f, 0.f};
        acc = __builtin_amdgcn_mfma_f32_16x16x32_bf16(areg[k][0], bfr[0][nt], acc, 0, 0, 0);
        acc = __builtin_amdgcn_mfma_f32_16x16x32_bf16(areg[k][1], bfr[1][nt], acc, 0, 0, 0);
        // zero-padded t rows contribute 0 to both sums
        float pp = acc[0] + acc[1] + acc[2] + acc[3];
        float qq = acc[0]*acc[0] + acc[1]*acc[1] + acc[2]*acc[2] + acc[3]*acc[3];
        pp += __shfl_xor(pp, 16); pp += __shfl_xor(pp, 32);   // all-reduce
        qq += __shfl_xor(qq, 16); qq += __shfl_xor(qq, 32);
        pr[nt] = pp; qr[nt] = qq;
      }
      if (ATOMIC) {
        if ((l & 48) == 0) {
          #pragma unroll
          for (int nt = 0; nt < 4; ++nt) {
            int col = v * 64 + nt * 16 + t_lane;
            atomicAdd(&pb[col], pr[nt]);
            atomicAdd(&pb[1600 + col], qr[nt]);
          }
        }
      } else {
        // full-wave 256B coalesced partial stores (lane picks its fragment)
        float pv = (grp & 2) ? ((grp & 1) ? pr[3] : pr[2]) : ((grp & 1) ? pr[1] : pr[0]);
        float qv = (grp & 2) ? ((grp & 1) ? qr[3] : qr[2]) : ((grp & 1) ? qr[1] : qr[0]);
        pb[v * 64 + l] = pv;
        pb[1600 + v * 64 + l] = qv;
      }
    }
  }
}

// reduce part[1216][3200] -> wsum_final[3200]; 200 blocks x (16 cols x 16 chunks)
__global__ __launch_bounds__(256) void k_red(const float* __restrict__ part,
                                             float* __restrict__ wsum) {
  __shared__ float red[16 * 17];
  int col0 = blockIdx.x * 16;
  int c = TID & 15, ch = TID >> 4;        // ch 0..15, 76 rows each
  float s = 0.f;
  int r0 = ch * 76;
  #pragma unroll 4
  for (int i = 0; i < 76; ++i) s += part[(r0 + i) * 3200 + col0 + c];
  red[ch * 17 + c] = s;
  __syncthreads();
  if (TID < 16) {
    float t = 0.f;
    #pragma unroll
    for (int j = 0; j < 16; ++j) t += red[j * 17 + TID];
    wsum[col0 + TID] = t;
  }
}

// BN fold once: entry {f32 scale, bf16 off, u16 s2*16} at permuted index d*25+v
__global__ void k_epi(const float* __restrict__ wsum, const float* __restrict__ gamma,
                      const float* __restrict__ beta, const int* __restrict__ shift_out,
                      u64* __restrict__ epi_g) {
  int k = blockIdx.x * 256 + TID;
  if (k >= Fin) return;
  int s2 = shift_out[k];
  float sm = wsum[s2] * (1.0f / RowsT);
  float sq = wsum[1600 + s2] * (1.0f / RowsT);
  float rstd = rsqrtf(fmaxf(sq - sm * sm, 0.f) + EPSv);
  float sc = gamma[k] * rstd;             // lin_b provably cancels in BN
  int d = k & 63, v = k >> 6;
  epi_g[d * 25 + v] = (u64)__float_as_uint(sc)
                    | ((u64)f2b(beta[k] - sm * sc) << 32)
                    | ((u64)(u32)(s2 * 16) << 48);
}

// consumer: recompute y in-LDS; ylds[1600][16] with t-quad XOR swizzle
__global__ __launch_bounds__(512, 4) void k_main(
    const float* __restrict__ x, const u16* __restrict__ wv,
    const u32* __restrict__ combo_g, const u64* __restrict__ epi_g,
    float* __restrict__ out)
{
  // [0,51200) raw --overlay--> ylds; [51200,57600) combo; [57600,70400) epi
  // ylds element (col, t) at col*16 + (t ^ (((col>>2)&3)<<2)):
  //   writes: one aligned ds_write_b64 per (k,nt), 32-bank coverage per inst
  //   reads : random s2 bits -> uniform banks
  __shared__ __align__(16) unsigned char smem[70400];
  u16* raw   = reinterpret_cast<u16*>(smem);
  u16* ylds  = reinterpret_cast<u16*>(smem);
  u32* combo = reinterpret_cast<u32*>(smem + 51200);
  u64* epi   = reinterpret_cast<u64*>(smem + 57600);

  int bid = blockIdx.x;
  int n = bid / NTB, tb = bid - n * NTB;
  int t0 = tb * TBR;
  int validg = min(TBR, Tt - t0) * 25;

  stage_raw(x, n, t0, validg, raw);
  #pragma unroll
  for (int i = 0; i < 4; ++i) {
    int j = TID + i * 512;
    if (j < Fin) {
      combo[j] = combo_g[j];
      epi[j] = epi_g[j];
    }
  }
  __syncthreads();

  // phase 2: hoist A fragments (bfr NOT yet live); raw dies after this
  int w = TID >> 6, l = TID & 63, grp = l >> 4, t_lane = l & 15;
  bf16x8 areg[4][2];
  #pragma unroll
  for (int k = 0; k < 4; ++k) {
    int v = w + 8 * k;
    if (v < Vv) {
      areg[k][0] = build_a(raw, combo, v, 0, t_lane, grp);
      areg[k][1] = build_a(raw, combo, v, 1, t_lane, grp);
    }
  }
  __syncthreads();  // overlay region now ylds

  // phase 3: B fragments now, then MFMA -> swizzled ylds (b64 stores)
  bf16x8 bfr[2][4];
  load_bfr_g(wv, bfr);

  #pragma unroll
  for (int k = 0; k < 4; ++k) {
    int v = w + 8 * k;
    if (v < Vv) {
      #pragma unroll
      for (int nt = 0; nt < 4; ++nt) {
        f32x4 acc = {0.f, 0.f, 0.f, 0.f};
        acc = __builtin_amdgcn_mfma_f32_16x16x32_bf16(areg[k][0], bfr[0][nt], acc, 0, 0, 0);
        acc = __builtin_amdgcn_mfma_f32_16x16x32_bf16(areg[k][1], bfr[1][nt], acc, 0, 0, 0);
        int col = v * 64 + nt * 16 + t_lane;
        int o = (col << 4) + ((grp ^ (t_lane >> 2)) << 2);  // swizzled t-quad, 8B-aligned
        *reinterpret_cast<u64*>(ylds + o) = pack4(acc[0], acc[1], acc[2], acc[3]);
      }
    }
  }
  __syncthreads();

  // epilogue: BN + residual (x re-read, L3-hot) + relu, float4 stores
  const int obase = n * 480000 + t0 * 25;
  #pragma unroll
  for (int it = 0; it < 13; ++it) {
    int g = TID + it * 512;               // float4 group id
    if (g < 6400) {
      int d = g / 100;
      int f0 = (g - d * 100) * 4;
      if (f0 < validg) {
        const float4 xr = *reinterpret_cast<const float4*>(x + obase + d * 7500 + f0);
        float4 o;
        float* op = &o.x;
        const float* xp = &xr.x;
        #pragma unroll
        for (int e = 0; e < 4; ++e) {
          int f = f0 + e;
          int t = f / 25;
          int v = f - t * 25;
          u64 ep = epi[d * 25 + v];       // LDS
          float sc = __uint_as_float((u32)ep);
          float of = b2f((u16)(ep >> 32));
          u32 bk = (u32)(ep >> 48);       // s2*16
          int elem = (int)bk + (t ^ (((bk >> 6) & 3) << 2));
          float y = b2f(ylds[elem]);
          op[e] = fmaxf(fmaf(y, sc, of) + xp[e], 0.f);
        }
        *reinterpret_cast<float4*>(out + obase + d * 7500 + f0) = o;
      }
    }
  }
}

extern "C" void kernel_launch(void* const* d_in, const int* in_sizes, int n_in,
                              void* d_out, int out_size, void* d_ws, size_t ws_size,
                              hipStream_t stream) {
  (void)in_sizes; (void)n_in; (void)out_size;
  const float* x        = (const float*)d_in[0];
  const float* lin_w    = (const float*)d_in[1];
  // d_in[2] = lin_b: provably cancels in BatchNorm -> unused
  const float* feat_mask= (const float*)d_in[3];
  const float* gamma    = (const float*)d_in[4];
  const float* beta     = (const float*)d_in[5];
  const int*   shift_in = (const int*)d_in[6];
  const int*   shift_out= (const int*)d_in[7];
  float* wsum   = (float*)d_ws;
  u64*   epi_g  = (u64*)((char*)d_ws + WS_EPI);
  u16*   wv     = (u16*)((char*)d_ws + WS_WV);
  u32*   combo_g= (u32*)((char*)d_ws + WS_COMBO);
  float* part   = (float*)((char*)d_ws + WS_PART);

  k_wv<<<13, 256, 0, stream>>>(lin_w, feat_mask, shift_in, wsum, wv, combo_g);
  if (ws_size >= WS_NEED_PART) {
    k_stats<0><<<NBLK, 512, 0, stream>>>(x, wv, combo_g, part);
    k_red<<<200, 256, 0, stream>>>(part, wsum);
  } else {
    k_stats<1><<<NBLK, 512, 0, stream>>>(x, wv, combo_g, wsum);
  }
  k_epi <<<7, 256, 0, stream>>>(wsum, gamma, beta, shift_out, epi_g);
  k_main<<<NBLK, 512, 0, stream>>>(x, wv, combo_g, epi_g, (float*)d_out);
}

// Round 13
// 111.633 us; speedup vs baseline: 2.1300x; 1.0282x over previous
//
#include <hip/hip_runtime.h>

typedef __bf16 bf16x8 __attribute__((ext_vector_type(8)));
typedef float f32x4 __attribute__((ext_vector_type(4)));
typedef unsigned short u16;
typedef unsigned int u32;
typedef unsigned long long u64;
typedef u16 u16x8 __attribute__((ext_vector_type(8)));

#define TID ((int)threadIdx.x)

constexpr int Nn = 64, Tt = 300, Vv = 25;
constexpr int Fin = 1600;           // V*C = V*CO
constexpr int RowsT = 19200;        // N*T
constexpr int TBR = 16;             // k_stats t-rows per block
constexpr int NTB = 19;             // ceil(300/16)
constexpr int NBLK = Nn * NTB;      // 1216 stats tiles
constexpr int RAWE = 64 * TBR * 25; // 25600 bf16 (51200 B) for k_stats
constexpr int TB2 = 8, NTB2 = 38;   // k_main t-rows per block; 37*8+4
constexpr int NBLK2 = Nn * NTB2;    // 2432 main tiles
constexpr float EPSv = 1e-5f;

// d_ws layout:
//   [0, 12800)            wsum_final: 1600 sum + 1600 sumsq (f32)
//   [12800, 25600)        epi_g: u64[1600] folded BN, permuted to d*25+v
//   [25600, 33792)        wv:    u16[4096] plain-W B-fragments (v-independent)
//   [33792, 40192)        combo_g:  u32[1600] 400-stride offs | mask  (k_stats)
//   [40192, 46592)        combo2_g: u32[1600] 200-stride offs | mask  (k_main)
//   [46592, 15611392)     part: f32[1216][3200] block partials (15.56 MB)
constexpr int WS_EPI    = 12800;
constexpr int WS_WV     = 25600;
constexpr int WS_COMBO  = 33792;
constexpr int WS_COMBO2 = 40192;
constexpr int WS_PART   = 46592;
constexpr size_t WS_NEED_PART = (size_t)WS_PART + (size_t)NBLK * 3200 * 4;

__device__ __forceinline__ u16 f2b(float f) {
  u32 u = __float_as_uint(f);
  return (u16)((u + 0x7fffu + ((u >> 16) & 1u)) >> 16); // RNE
}
__device__ __forceinline__ float b2f(u16 h) {
  return __uint_as_float(((u32)h) << 16);
}
__device__ __forceinline__ u64 pack4(float a, float b, float c, float d) {
  return (u64)f2b(a) | ((u64)f2b(b) << 16) | ((u64)f2b(c) << 32) | ((u64)f2b(d) << 48);
}

// ---- k_stats staging: x-tile bf16, layout [c][t*25+v], t<16 ----
__device__ __forceinline__ void stage_raw16(const float* __restrict__ x,
                                            int n, int t0, int validg, u16* raw) {
  const int base = n * 480000 + t0 * 25;
  #pragma unroll
  for (int i = 0; i < 13; ++i) {
    int q = TID + i * 512;                // float4 group id, 0..6399
    if (q < 6400) {
      int c = q / 100;
      int g4 = (q - c * 100) * 4;         // 16B aligned
      float4 xv = make_float4(0.f, 0.f, 0.f, 0.f);
      if (g4 < validg)                    // validg divisible by 4
        xv = *reinterpret_cast<const float4*>(x + base + c * 7500 + g4);
      *reinterpret_cast<u64*>(raw + q * 4) = pack4(xv.x, xv.y, xv.z, xv.w);
    }
  }
}

// ---- k_main staging: x-tile bf16, layout [c][t*25+v], t<8 (c-stride 200) ----
__device__ __forceinline__ void stage_raw8(const float* __restrict__ x,
                                           int n, int t0, int validg, u16* raw) {
  const int base = n * 480000 + t0 * 25;
  #pragma unroll
  for (int i = 0; i < 7; ++i) {
    int q = TID + i * 512;                // float4 group id, 0..3199
    if (q < 3200) {
      int c = q / 50;
      int g4 = (q - c * 50) * 4;          // 0..196
      float4 xv = make_float4(0.f, 0.f, 0.f, 0.f);
      if (g4 < validg)                    // validg in {200,100}, divisible by 4
        xv = *reinterpret_cast<const float4*>(x + base + c * 7500 + g4);
      *reinterpret_cast<u64*>(raw + q * 4) = pack4(xv.x, xv.y, xv.z, xv.w);
    }
  }
}

// 8 v-independent B fragments (plain W) -> registers, one coalesced pass
__device__ __forceinline__ void load_bfr_g(const u16* __restrict__ wv, bf16x8 bfr[2][4]) {
  int l = TID & 63;
  #pragma unroll
  for (int ks = 0; ks < 2; ++ks)
    #pragma unroll
    for (int nt = 0; nt < 4; ++nt)
      bfr[ks][nt] = *reinterpret_cast<const bf16x8*>(wv + ((((ks << 2) | nt) << 9) + l * 8));
}

// A fragment: gather+mask from LDS; t=lane&15
__device__ __forceinline__ bf16x8 build_a(const u16* raw, const u32* __restrict__ combo,
                                          int v, int ks, int t, int grp) {
  int jb = v * 64 + ks * 32 + grp * 8;
  bf16x8 a;
  #pragma unroll
  for (int i = 0; i < 8; ++i) {
    u32 cb = combo[jb + i];
    float m = __uint_as_float((cb & 0xffffu) << 16);
    float xv = b2f(raw[(cb >> 16) + t * 25]);
    a[i] = (__bf16)(xv * m);
  }
  return a;
}

// ---- precompute: zero wsum; both combo tables (tanh hoisted); W B-fragments ----
__global__ void k_wv(const float* __restrict__ lin_w, const float* __restrict__ feat_mask,
                     const int* __restrict__ shift_in, float* __restrict__ wsum,
                     u16* __restrict__ wv, u32* __restrict__ combo_g,
                     u32* __restrict__ combo2_g) {
  int gid = blockIdx.x * 256 + TID;       // grid 13*256 = 3328
  if (gid < 3200) wsum[gid] = 0.f;        // atomic-mode target (re-zeroed each launch)
  if (gid < Fin) {
    int s = shift_in[gid];                               // source col v2*64+c2
    float m = tanhf(feat_mask[gid]) + 1.0f;
    u16 mb = f2b(m);
    combo_g[gid]  = (((u32)((s & 63) * 400 + (s >> 6))) << 16) | mb;
    combo2_g[gid] = (((u32)((s & 63) * 200 + (s >> 6))) << 16) | mb;
  }
  if (gid >= 2048 && gid < 2560) {        // 512 threads build B fragments
    int t = gid - 2048;
    int l = t & 63, nt = (t >> 6) & 3, ks = t >> 8;
    int c0 = ks * 32 + (l >> 4) * 8, d = nt * 16 + (l & 15);
    u16x8 o8;
    #pragma unroll
    for (int i = 0; i < 8; ++i) o8[i] = f2b(lin_w[(c0 + i) * 64 + d]);
    *reinterpret_cast<u16x8*>(wv + ((((ks << 2) | nt) << 9) + l * 8)) = o8;
  }
}

// stats pass (TBR=16): ATOMIC=0 stores block partials; ATOMIC=1 atomicAdd fallback
template <int ATOMIC>
__global__ __launch_bounds__(512, 4) void k_stats(
    const float* __restrict__ x, const u16* __restrict__ wv,
    const u32* __restrict__ combo_g, float* __restrict__ target)
{
  __shared__ __align__(16) u16 raw[RAWE];   // 51.2 KB
  int bid = blockIdx.x;                   // 0..1215, 1 tile each
  int n = bid / NTB, tb = bid - n * NTB;
  int t0 = tb * TBR;
  int validg = min(TBR, Tt - t0) * 25;
  int w = TID >> 6, l = TID & 63;
  int t_lane = l & 15, grp = l >> 4;

  stage_raw16(x, n, t0, validg, raw);
  __syncthreads();

  // phase 2: hoist A fragments (bfr NOT yet live)
  bf16x8 areg[4][2];
  #pragma unroll
  for (int k = 0; k < 4; ++k) {
    int v = w + 8 * k;
    if (v < Vv) {
      areg[k][0] = build_a(raw, combo_g, v, 0, t_lane, grp);
      areg[k][1] = build_a(raw, combo_g, v, 1, t_lane, grp);
    }
  }

  // phase 3: B fragments now, then MFMA + stat reduce
  bf16x8 bfr[2][4];
  load_bfr_g(wv, bfr);

  float* pb = target + (ATOMIC ? 0 : bid * 3200);
  #pragma unroll
  for (int k = 0; k < 4; ++k) {
    int v = w + 8 * k;
    if (v < Vv) {
      float pr[4], qr[4];
      #pragma unroll
      for (int nt = 0; nt < 4; ++nt) {
        f32x4 acc = {0.f, 0.f, 0.f, 0.f};
        acc = __builtin_amdgcn_mfma_f32_16x16x32_bf16(areg[k][0], bfr[0][nt], acc, 0, 0, 0);
        acc = __builtin_amdgcn_mfma_f32_16x16x32_bf16(areg[k][1], bfr[1][nt], acc, 0, 0, 0);
        // zero-padded t rows contribute 0 to both sums
        float pp = acc[0] + acc[1] + acc[2] + acc[3];
        float qq = acc[0]*acc[0] + acc[1]*acc[1] + acc[2]*acc[2] + acc[3]*acc[3];
        pp += __shfl_xor(pp, 16); pp += __shfl_xor(pp, 32);   // all-reduce
        qq += __shfl_xor(qq, 16); qq += __shfl_xor(qq, 32);
        pr[nt] = pp; qr[nt] = qq;
      }
      if (ATOMIC) {
        if ((l & 48) == 0) {
          #pragma unroll
          for (int nt = 0; nt < 4; ++nt) {
            int col = v * 64 + nt * 16 + t_lane;
            atomicAdd(&pb[col], pr[nt]);
            atomicAdd(&pb[1600 + col], qr[nt]);
          }
        }
      } else {
        // full-wave 256B coalesced partial stores (lane picks its fragment)
        float pv = (grp & 2) ? ((grp & 1) ? pr[3] : pr[2]) : ((grp & 1) ? pr[1] : pr[0]);
        float qv = (grp & 2) ? ((grp & 1) ? qr[3] : qr[2]) : ((grp & 1) ? qr[1] : qr[0]);
        pb[v * 64 + l] = pv;
        pb[1600 + v * 64 + l] = qv;
      }
    }
  }
}

// reduce part[1216][3200] -> wsum_final[3200]; 200 blocks x (16 cols x 16 chunks)
__global__ __launch_bounds__(256) void k_red(const float* __restrict__ part,
                                             float* __restrict__ wsum) {
  __shared__ float red[16 * 17];
  int col0 = blockIdx.x * 16;
  int c = TID & 15, ch = TID >> 4;        // ch 0..15, 76 rows each
  float s = 0.f;
  int r0 = ch * 76;
  #pragma unroll 4
  for (int i = 0; i < 76; ++i) s += part[(r0 + i) * 3200 + col0 + c];
  red[ch * 17 + c] = s;
  __syncthreads();
  if (TID < 16) {
    float t = 0.f;
    #pragma unroll
    for (int j = 0; j < 16; ++j) t += red[j * 17 + TID];
    wsum[col0 + TID] = t;
  }
}

// BN fold once: entry {f32 scale, bf16 off, u16 s2*8} at permuted index d*25+v
__global__ void k_epi(const float* __restrict__ wsum, const float* __restrict__ gamma,
                      const float* __restrict__ beta, const int* __restrict__ shift_out,
                      u64* __restrict__ epi_g) {
  int k = blockIdx.x * 256 + TID;
  if (k >= Fin) return;
  int s2 = shift_out[k];
  float sm = wsum[s2] * (1.0f / RowsT);
  float sq = wsum[1600 + s2] * (1.0f / RowsT);
  float rstd = rsqrtf(fmaxf(sq - sm * sm, 0.f) + EPSv);
  float sc = gamma[k] * rstd;             // lin_b provably cancels in BN
  int d = k & 63, v = k >> 6;
  epi_g[d * 25 + v] = (u64)__float_as_uint(sc)
                    | ((u64)f2b(beta[k] - sm * sc) << 32)
                    | ((u64)(u32)(s2 * 8) << 48);
}

// consumer (TB2=8): raw stays ALIVE -> residual from LDS bf16 x; single x pass
__global__ __launch_bounds__(512, 4) void k_main(
    const float* __restrict__ x, const u16* __restrict__ wv,
    const u32* __restrict__ combo2_g, const u64* __restrict__ epi_g,
    float* __restrict__ out)
{
  // [0,25600) raw u16[64][200] | [25600,51200) ylds u16[1600][8]
  // [51200,57600) combo | [57600,70400) epi     -- 70.4 KB, 2 blocks/CU
  // ylds element (col,t) at col*8 + (t ^ ((col&1)<<2)): aligned b64 writes,
  // 2-way-max write banks (free), read banks randomized by s2 bits
  __shared__ __align__(16) unsigned char smem[70400];
  u16* raw   = reinterpret_cast<u16*>(smem);
  u16* ylds  = reinterpret_cast<u16*>(smem + 25600);
  u32* combo = reinterpret_cast<u32*>(smem + 51200);
  u64* epi   = reinterpret_cast<u64*>(smem + 57600);

  int bid = blockIdx.x;
  int n = bid / NTB2, tb = bid - n * NTB2;
  int t0 = tb * TB2;
  int validg = min(TB2, Tt - t0) * 25;    // 200 or 100 (tail tb=37)

  stage_raw8(x, n, t0, validg, raw);
  #pragma unroll
  for (int i = 0; i < 4; ++i) {
    int j = TID + i * 512;
    if (j < Fin) {
      combo[j] = combo2_g[j];
      epi[j] = epi_g[j];
    }
  }
  __syncthreads();

  // MFMA phase: no areg hoist (raw persists); rows t>=8 garbage, never read
  int w = TID >> 6, l = TID & 63, grp = l >> 4, t_lane = l & 15;
  bf16x8 bfr[2][4];
  load_bfr_g(wv, bfr);

  #pragma unroll
  for (int k = 0; k < 4; ++k) {
    int v = w + 8 * k;
    if (v < Vv) {
      bf16x8 a0 = build_a(raw, combo, v, 0, t_lane, grp);
      bf16x8 a1 = build_a(raw, combo, v, 1, t_lane, grp);
      #pragma unroll
      for (int nt = 0; nt < 4; ++nt) {
        f32x4 acc = {0.f, 0.f, 0.f, 0.f};
        acc = __builtin_amdgcn_mfma_f32_16x16x32_bf16(a0, bfr[0][nt], acc, 0, 0, 0);
        acc = __builtin_amdgcn_mfma_f32_16x16x32_bf16(a1, bfr[1][nt], acc, 0, 0, 0);
        if (grp < 2) {                    // rows t = grp*4+j < 8
          int col = v * 64 + nt * 16 + t_lane;
          int o = (col << 3) + ((grp ^ (col & 1)) << 2);
          *reinterpret_cast<u64*>(ylds + o) = pack4(acc[0], acc[1], acc[2], acc[3]);
        }
      }
    }
  }
  __syncthreads();

  // epilogue: BN + residual (from raw bf16, NO x re-read) + relu, float4 stores
  const int obase = n * 480000 + t0 * 25;
  #pragma unroll
  for (int it = 0; it < 7; ++it) {
    int g = TID + it * 512;               // float4 group id, 0..3199
    if (g < 3200) {
      int d = g / 50;
      int f0 = (g - d * 50) * 4;          // 0..196
      if (f0 < validg) {
        float4 o;
        float* op = &o.x;
        #pragma unroll
        for (int e = 0; e < 4; ++e) {
          int f = f0 + e;
          int t = f / 25;
          int v = f - t * 25;
          u64 ep = epi[d * 25 + v];       // LDS
          float sc = __uint_as_float((u32)ep);
          float of = b2f((u16)(ep >> 32));
          u32 bk = (u32)(ep >> 48);       // s2*8
          float y = b2f(ylds[(int)bk + (t ^ (((bk >> 3) & 1) << 2))]);
          float xr = b2f(raw[d * 200 + f]);
          op[e] = fmaxf(fmaf(y, sc, of) + xr, 0.f);
        }
        *reinterpret_cast<float4*>(out + obase + d * 7500 + f0) = o;
      }
    }
  }
}

extern "C" void kernel_launch(void* const* d_in, const int* in_sizes, int n_in,
                              void* d_out, int out_size, void* d_ws, size_t ws_size,
                              hipStream_t stream) {
  (void)in_sizes; (void)n_in; (void)out_size;
  const float* x        = (const float*)d_in[0];
  const float* lin_w    = (const float*)d_in[1];
  // d_in[2] = lin_b: provably cancels in BatchNorm -> unused
  const float* feat_mask= (const float*)d_in[3];
  const float* gamma    = (const float*)d_in[4];
  const float* beta     = (const float*)d_in[5];
  const int*   shift_in = (const int*)d_in[6];
  const int*   shift_out= (const int*)d_in[7];
  float* wsum    = (float*)d_ws;
  u64*   epi_g   = (u64*)((char*)d_ws + WS_EPI);
  u16*   wv      = (u16*)((char*)d_ws + WS_WV);
  u32*   combo_g = (u32*)((char*)d_ws + WS_COMBO);
  u32*   combo2_g= (u32*)((char*)d_ws + WS_COMBO2);
  float* part    = (float*)((char*)d_ws + WS_PART);

  k_wv<<<13, 256, 0, stream>>>(lin_w, feat_mask, shift_in, wsum, wv, combo_g, combo2_g);
  if (ws_size >= WS_NEED_PART) {
    k_stats<0><<<NBLK, 512, 0, stream>>>(x, wv, combo_g, part);
    k_red<<<200, 256, 0, stream>>>(part, wsum);
  } else {
    k_stats<1><<<NBLK, 512, 0, stream>>>(x, wv, combo_g, wsum);
  }
  k_epi <<<7, 256, 0, stream>>>(wsum, gamma, beta, shift_out, epi_g);
  k_main<<<NBLK2, 512, 0, stream>>>(x, wv, combo2_g, epi_g, (float*)d_out);
}

// Round 14
// 110.756 us; speedup vs baseline: 2.1469x; 1.0079x over previous
//
#include <hip/hip_runtime.h>

typedef __bf16 bf16x8 __attribute__((ext_vector_type(8)));
typedef __bf16 bf16x4 __attribute__((ext_vector_type(4)));
typedef float f32x4 __attribute__((ext_vector_type(4)));
typedef unsigned short u16;
typedef unsigned int u32;
typedef unsigned long long u64;
typedef u16 u16x8 __attribute__((ext_vector_type(8)));

#define TID ((int)threadIdx.x)

constexpr int Nn = 64, Tt = 300, Vv = 25;
constexpr int Fin = 1600;           // V*C = V*CO
constexpr int RowsT = 19200;        // N*T
constexpr int TBR = 16;             // k_stats t-rows per block
constexpr int NTB = 19;             // ceil(300/16)
constexpr int NBLK = Nn * NTB;      // 1216 stats tiles
constexpr int RAWE = 64 * TBR * 25; // 25600 bf16 (51200 B) for k_stats
constexpr int TB2 = 8, NTB2 = 38;   // k_main t-rows per block; 37*8+4
constexpr int NBLK2 = Nn * NTB2;    // 2432 main tiles
constexpr float EPSv = 1e-5f;

// d_ws layout:
//   [0, 12800)            wsum_final: 1600 sum + 1600 sumsq (f32)
//   [12800, 25600)        epi_g: u64[1600] folded BN, permuted to d*25+v
//   [25600, 33792)        wv:    u16[4096] plain-W B-fragments (v-independent)
//   [33792, 40192)        combo_g:  u32[1600] 400-stride offs | mask  (k_stats)
//   [40192, 46592)        combo2_g: u32[1600] 200-stride offs | mask  (k_main)
//   [46592, 15611392)     part: f32[1216][3200] block partials (15.56 MB)
constexpr int WS_EPI    = 12800;
constexpr int WS_WV     = 25600;
constexpr int WS_COMBO  = 33792;
constexpr int WS_COMBO2 = 40192;
constexpr int WS_PART   = 46592;
constexpr size_t WS_NEED_PART = (size_t)WS_PART + (size_t)NBLK * 3200 * 4;

__device__ __forceinline__ u16 f2b(float f) {
  u32 u = __float_as_uint(f);
  return (u16)((u + 0x7fffu + ((u >> 16) & 1u)) >> 16); // RNE (cold paths only)
}
__device__ __forceinline__ float b2f(u16 h) {
  return __uint_as_float(((u32)h) << 16);
}
// native-cast pack: compiler emits v_cvt_pk_bf16_f32 pairs (RNE, bit-identical)
__device__ __forceinline__ u64 pack4(float a, float b, float c, float d) {
  bf16x4 r;
  r[0] = (__bf16)a; r[1] = (__bf16)b; r[2] = (__bf16)c; r[3] = (__bf16)d;
  return __builtin_bit_cast(u64, r);
}

// ---- k_stats staging: x-tile bf16, layout [c][t*25+v], t<16 ----
__device__ __forceinline__ void stage_raw16(const float* __restrict__ x,
                                            int n, int t0, int validg, u16* raw) {
  const int base = n * 480000 + t0 * 25;
  #pragma unroll
  for (int i = 0; i < 13; ++i) {
    int q = TID + i * 512;                // float4 group id, 0..6399
    if (q < 6400) {
      int c = q / 100;
      int g4 = (q - c * 100) * 4;         // 16B aligned
      float4 xv = make_float4(0.f, 0.f, 0.f, 0.f);
      if (g4 < validg)                    // validg divisible by 4
        xv = *reinterpret_cast<const float4*>(x + base + c * 7500 + g4);
      *reinterpret_cast<u64*>(raw + q * 4) = pack4(xv.x, xv.y, xv.z, xv.w);
    }
  }
}

// ---- k_main staging: x-tile bf16, layout [c][t*25+v], t<8 (c-stride 200) ----
__device__ __forceinline__ void stage_raw8(const float* __restrict__ x,
                                           int n, int t0, int validg, u16* raw) {
  const int base = n * 480000 + t0 * 25;
  #pragma unroll
  for (int i = 0; i < 7; ++i) {
    int q = TID + i * 512;                // float4 group id, 0..3199
    if (q < 3200) {
      int c = q / 50;
      int g4 = (q - c * 50) * 4;          // 0..196
      float4 xv = make_float4(0.f, 0.f, 0.f, 0.f);
      if (g4 < validg)                    // validg in {200,100}, divisible by 4
        xv = *reinterpret_cast<const float4*>(x + base + c * 7500 + g4);
      *reinterpret_cast<u64*>(raw + q * 4) = pack4(xv.x, xv.y, xv.z, xv.w);
    }
  }
}

// 8 v-independent B fragments (plain W) -> registers, one coalesced pass
__device__ __forceinline__ void load_bfr_g(const u16* __restrict__ wv, bf16x8 bfr[2][4]) {
  int l = TID & 63;
  #pragma unroll
  for (int ks = 0; ks < 2; ++ks)
    #pragma unroll
    for (int nt = 0; nt < 4; ++nt)
      bfr[ks][nt] = *reinterpret_cast<const bf16x8*>(wv + ((((ks << 2) | nt) << 9) + l * 8));
}

// A fragment: gather+mask from LDS; t=lane&15
__device__ __forceinline__ bf16x8 build_a(const u16* raw, const u32* __restrict__ combo,
                                          int v, int ks, int t, int grp) {
  int jb = v * 64 + ks * 32 + grp * 8;
  bf16x8 a;
  #pragma unroll
  for (int i = 0; i < 8; ++i) {
    u32 cb = combo[jb + i];
    float m = __uint_as_float((cb & 0xffffu) << 16);
    float xv = b2f(raw[(cb >> 16) + t * 25]);
    a[i] = (__bf16)(xv * m);
  }
  return a;
}

// ---- precompute: zero wsum; both combo tables (tanh hoisted); W B-fragments ----
__global__ void k_wv(const float* __restrict__ lin_w, const float* __restrict__ feat_mask,
                     const int* __restrict__ shift_in, float* __restrict__ wsum,
                     u16* __restrict__ wv, u32* __restrict__ combo_g,
                     u32* __restrict__ combo2_g) {
  int gid = blockIdx.x * 256 + TID;       // grid 13*256 = 3328
  if (gid < 3200) wsum[gid] = 0.f;        // atomic-mode target (re-zeroed each launch)
  if (gid < Fin) {
    int s = shift_in[gid];                               // source col v2*64+c2
    float m = tanhf(feat_mask[gid]) + 1.0f;
    u16 mb = f2b(m);
    combo_g[gid]  = (((u32)((s & 63) * 400 + (s >> 6))) << 16) | mb;
    combo2_g[gid] = (((u32)((s & 63) * 200 + (s >> 6))) << 16) | mb;
  }
  if (gid >= 2048 && gid < 2560) {        // 512 threads build B fragments
    int t = gid - 2048;
    int l = t & 63, nt = (t >> 6) & 3, ks = t >> 8;
    int c0 = ks * 32 + (l >> 4) * 8, d = nt * 16 + (l & 15);
    u16x8 o8;
    #pragma unroll
    for (int i = 0; i < 8; ++i) o8[i] = f2b(lin_w[(c0 + i) * 64 + d]);
    *reinterpret_cast<u16x8*>(wv + ((((ks << 2) | nt) << 9) + l * 8)) = o8;
  }
}

// stats pass (TBR=16): ATOMIC=0 stores block partials; ATOMIC=1 atomicAdd fallback
template <int ATOMIC>
__global__ __launch_bounds__(512, 4) void k_stats(
    const float* __restrict__ x, const u16* __restrict__ wv,
    const u32* __restrict__ combo_g, float* __restrict__ target)
{
  __shared__ __align__(16) u16 raw[RAWE];   // 51.2 KB
  int bid = blockIdx.x;                   // 0..1215, 1 tile each
  int n = bid / NTB, tb = bid - n * NTB;
  int t0 = tb * TBR;
  int validg = min(TBR, Tt - t0) * 25;
  int w = TID >> 6, l = TID & 63;
  int t_lane = l & 15, grp = l >> 4;

  stage_raw16(x, n, t0, validg, raw);
  __syncthreads();

  // phase 2: hoist A fragments (bfr NOT yet live)
  bf16x8 areg[4][2];
  #pragma unroll
  for (int k = 0; k < 4; ++k) {
    int v = w + 8 * k;
    if (v < Vv) {
      areg[k][0] = build_a(raw, combo_g, v, 0, t_lane, grp);
      areg[k][1] = build_a(raw, combo_g, v, 1, t_lane, grp);
    }
  }

  // phase 3: B fragments now, then MFMA + stat reduce
  bf16x8 bfr[2][4];
  load_bfr_g(wv, bfr);

  float* pb = target + (ATOMIC ? 0 : bid * 3200);
  #pragma unroll
  for (int k = 0; k < 4; ++k) {
    int v = w + 8 * k;
    if (v < Vv) {
      float pr[4], qr[4];
      #pragma unroll
      for (int nt = 0; nt < 4; ++nt) {
        f32x4 acc = {0.f, 0.f, 0.f, 0.f};
        acc = __builtin_amdgcn_mfma_f32_16x16x32_bf16(areg[k][0], bfr[0][nt], acc, 0, 0, 0);
        acc = __builtin_amdgcn_mfma_f32_16x16x32_bf16(areg[k][1], bfr[1][nt], acc, 0, 0, 0);
        // zero-padded t rows contribute 0 to both sums
        float pp = acc[0] + acc[1] + acc[2] + acc[3];
        float qq = acc[0]*acc[0] + acc[1]*acc[1] + acc[2]*acc[2] + acc[3]*acc[3];
        pp += __shfl_xor(pp, 16); pp += __shfl_xor(pp, 32);   // all-reduce
        qq += __shfl_xor(qq, 16); qq += __shfl_xor(qq, 32);
        pr[nt] = pp; qr[nt] = qq;
      }
      if (ATOMIC) {
        if ((l & 48) == 0) {
          #pragma unroll
          for (int nt = 0; nt < 4; ++nt) {
            int col = v * 64 + nt * 16 + t_lane;
            atomicAdd(&pb[col], pr[nt]);
            atomicAdd(&pb[1600 + col], qr[nt]);
          }
        }
      } else {
        // full-wave 256B coalesced partial stores (lane picks its fragment)
        float pv = (grp & 2) ? ((grp & 1) ? pr[3] : pr[2]) : ((grp & 1) ? pr[1] : pr[0]);
        float qv = (grp & 2) ? ((grp & 1) ? qr[3] : qr[2]) : ((grp & 1) ? qr[1] : qr[0]);
        pb[v * 64 + l] = pv;
        pb[1600 + v * 64 + l] = qv;
      }
    }
  }
}

// reduce part[1216][3200] -> wsum_final[3200]; 200 blocks x (16 cols x 16 chunks)
__global__ __launch_bounds__(256) void k_red(const float* __restrict__ part,
                                             float* __restrict__ wsum) {
  __shared__ float red[16 * 17];
  int col0 = blockIdx.x * 16;
  int c = TID & 15, ch = TID >> 4;        // ch 0..15, 76 rows each
  float s = 0.f;
  int r0 = ch * 76;
  #pragma unroll 4
  for (int i = 0; i < 76; ++i) s += part[(r0 + i) * 3200 + col0 + c];
  red[ch * 17 + c] = s;
  __syncthreads();
  if (TID < 16) {
    float t = 0.f;
    #pragma unroll
    for (int j = 0; j < 16; ++j) t += red[j * 17 + TID];
    wsum[col0 + TID] = t;
  }
}

// BN fold once: entry {f32 scale, bf16 off, u16 s2*8} at permuted index d*25+v
__global__ void k_epi(const float* __restrict__ wsum, const float* __restrict__ gamma,
                      const float* __restrict__ beta, const int* __restrict__ shift_out,
                      u64* __restrict__ epi_g) {
  int k = blockIdx.x * 256 + TID;
  if (k >= Fin) return;
  int s2 = shift_out[k];
  float sm = wsum[s2] * (1.0f / RowsT);
  float sq = wsum[1600 + s2] * (1.0f / RowsT);
  float rstd = rsqrtf(fmaxf(sq - sm * sm, 0.f) + EPSv);
  float sc = gamma[k] * rstd;             // lin_b provably cancels in BN
  int d = k & 63, v = k >> 6;
  epi_g[d * 25 + v] = (u64)__float_as_uint(sc)
                    | ((u64)f2b(beta[k] - sm * sc) << 32)
                    | ((u64)(u32)(s2 * 8) << 48);
}

// consumer (TB2=8): raw stays ALIVE -> residual from LDS bf16 x; single x pass
__global__ __launch_bounds__(512, 4) void k_main(
    const float* __restrict__ x, const u16* __restrict__ wv,
    const u32* __restrict__ combo2_g, const u64* __restrict__ epi_g,
    float* __restrict__ out)
{
  // [0,25600) raw u16[64][200] | [25600,51200) ylds u16[1600][8]
  // [51200,57600) combo | [57600,70400) epi     -- 70.4 KB, 2 blocks/CU
  // ylds element (col,t) at col*8 + (t ^ ((col&1)<<2)): aligned b64 writes,
  // 2-way-max write banks (free), read banks randomized by s2 bits
  __shared__ __align__(16) unsigned char smem[70400];
  u16* raw   = reinterpret_cast<u16*>(smem);
  u16* ylds  = reinterpret_cast<u16*>(smem + 25600);
  u32* combo = reinterpret_cast<u32*>(smem + 51200);
  u64* epi   = reinterpret_cast<u64*>(smem + 57600);

  int bid = blockIdx.x;
  int n = bid / NTB2, tb = bid - n * NTB2;
  int t0 = tb * TB2;
  int validg = min(TB2, Tt - t0) * 25;    // 200 or 100 (tail tb=37)

  stage_raw8(x, n, t0, validg, raw);
  #pragma unroll
  for (int i = 0; i < 4; ++i) {
    int j = TID + i * 512;
    if (j < Fin) {
      combo[j] = combo2_g[j];
      epi[j] = epi_g[j];
    }
  }
  __syncthreads();

  // MFMA phase: no areg hoist (raw persists); rows t>=8 garbage, never read
  int w = TID >> 6, l = TID & 63, grp = l >> 4, t_lane = l & 15;
  bf16x8 bfr[2][4];
  load_bfr_g(wv, bfr);

  #pragma unroll
  for (int k = 0; k < 4; ++k) {
    int v = w + 8 * k;
    if (v < Vv) {
      bf16x8 a0 = build_a(raw, combo, v, 0, t_lane, grp);
      bf16x8 a1 = build_a(raw, combo, v, 1, t_lane, grp);
      #pragma unroll
      for (int nt = 0; nt < 4; ++nt) {
        f32x4 acc = {0.f, 0.f, 0.f, 0.f};
        acc = __builtin_amdgcn_mfma_f32_16x16x32_bf16(a0, bfr[0][nt], acc, 0, 0, 0);
        acc = __builtin_amdgcn_mfma_f32_16x16x32_bf16(a1, bfr[1][nt], acc, 0, 0, 0);
        if (grp < 2) {                    // rows t = grp*4+j < 8
          int col = v * 64 + nt * 16 + t_lane;
          int o = (col << 3) + ((grp ^ (col & 1)) << 2);
          *reinterpret_cast<u64*>(ylds + o) = pack4(acc[0], acc[1], acc[2], acc[3]);
        }
      }
    }
  }
  __syncthreads();

  // epilogue: BN + residual (from raw bf16, NO x re-read) + relu, float4 stores
  const int obase = n * 480000 + t0 * 25;
  #pragma unroll
  for (int it = 0; it < 7; ++it) {
    int g = TID + it * 512;               // float4 group id, 0..3199
    if (g < 3200) {
      int d = g / 50;
      int f0 = (g - d * 50) * 4;          // 0..196
      if (f0 < validg) {
        float4 o;
        float* op = &o.x;
        #pragma unroll
        for (int e = 0; e < 4; ++e) {
          int f = f0 + e;
          int t = f / 25;
          int v = f - t * 25;
          u64 ep = epi[d * 25 + v];       // LDS
          float sc = __uint_as_float((u32)ep);
          float of = b2f((u16)(ep >> 32));
          u32 bk = (u32)(ep >> 48);       // s2*8
          float y = b2f(ylds[(int)bk + (t ^ (((bk >> 3) & 1) << 2))]);
          float xr = b2f(raw[d * 200 + f]);
          op[e] = fmaxf(fmaf(y, sc, of) + xr, 0.f);
        }
        *reinterpret_cast<float4*>(out + obase + d * 7500 + f0) = o;
      }
    }
  }
}

extern "C" void kernel_launch(void* const* d_in, const int* in_sizes, int n_in,
                              void* d_out, int out_size, void* d_ws, size_t ws_size,
                              hipStream_t stream) {
  (void)in_sizes; (void)n_in; (void)out_size;
  const float* x        = (const float*)d_in[0];
  const float* lin_w    = (const float*)d_in[1];
  // d_in[2] = lin_b: provably cancels in BatchNorm -> unused
  const float* feat_mask= (const float*)d_in[3];
  const float* gamma    = (const float*)d_in[4];
  const float* beta     = (const float*)d_in[5];
  const int*   shift_in = (const int*)d_in[6];
  const int*   shift_out= (const int*)d_in[7];
  float* wsum    = (float*)d_ws;
  u64*   epi_g   = (u64*)((char*)d_ws + WS_EPI);
  u16*   wv      = (u16*)((char*)d_ws + WS_WV);
  u32*   combo_g = (u32*)((char*)d_ws + WS_COMBO);
  u32*   combo2_g= (u32*)((char*)d_ws + WS_COMBO2);
  float* part    = (float*)((char*)d_ws + WS_PART);

  k_wv<<<13, 256, 0, stream>>>(lin_w, feat_mask, shift_in, wsum, wv, combo_g, combo2_g);
  if (ws_size >= WS_NEED_PART) {
    k_stats<0><<<NBLK, 512, 0, stream>>>(x, wv, combo_g, part);
    k_red<<<200, 256, 0, stream>>>(part, wsum);
  } else {
    k_stats<1><<<NBLK, 512, 0, stream>>>(x, wv, combo_g, wsum);
  }
  k_epi <<<7, 256, 0, stream>>>(wsum, gamma, beta, shift_out, epi_g);
  k_main<<<NBLK2, 512, 0, stream>>>(x, wv, combo2_g, epi_g, (float*)d_out);
}